// Round 7
// baseline (851.483 us; speedup 1.0000x reference)
//
#include <hip/hip_runtime.h>
#include <hip/hip_bf16.h>

#define D 1024
#define SLEN 2048
#define BS 16
#define MROWS (BS*SLEN)   // 32768

typedef __attribute__((ext_vector_type(8))) short short8;
typedef __attribute__((ext_vector_type(4))) float f32x4;

__device__ __forceinline__ short f2bf(float f) {
  __hip_bfloat16 h = __float2bfloat16(f);
  return __builtin_bit_cast(short, h);
}

// non-temporal float4 load: streaming data (zero reuse) -> don't allocate in
// L2/L3 so the 2 MB WkT stays L2-resident for the B stream.
__device__ __forceinline__ float4 ntload4(const float* p) {
  f32x4 v = __builtin_nontemporal_load((const f32x4*)p);
  float4 r; r.x = v.x; r.y = v.y; r.z = v.z; r.w = v.w; return r;
}

__device__ __forceinline__ short8 pack8(const float4& a, const float4& b) {
  short8 p;
  p[0]=f2bf(a.x); p[1]=f2bf(a.y); p[2]=f2bf(a.z); p[3]=f2bf(a.w);
  p[4]=f2bf(b.x); p[5]=f2bf(b.y); p[6]=f2bf(b.z); p[7]=f2bf(b.w);
  return p;
}

// ---------------- Kernel 1: Wk (k,n) fp32 -> blocked bf16 WkT ----------------
// WkT[(u*1024 + n)*8 + j] = bf16(Wk[(u*8+j)*1024 + n]), u=0..127.
// 16B slot (u,n) = B[n][k=u*8..u*8+7] = one MFMA B k-unit.
__global__ __launch_bounds__(256) void wk_prep(const float* __restrict__ Wk,
                                               short* __restrict__ WkT) {
  const int g = blockIdx.x;        // 0..127
  const int t = threadIdx.x;
#pragma unroll
  for (int it = 0; it < 4; ++it) {
    const int n = it*256 + t;
    short8 p;
#pragma unroll
    for (int j = 0; j < 8; ++j)
      p[j] = f2bf(Wk[(size_t)(g*8 + j)*D + n]);
    *(short8*)(WkT + ((size_t)g*D + n)*8) = p;
  }
}

// ---------------- Kernel 2: energy GEMM v3 ----------------
// 256 blocks x 1024 thr (16 waves). Block = 128 rows x full N=1024.
// Wave tile 128x64 (fa=8, fb=4, acc=128 regs): B L1/L2 traffic halves to
// 512 MB (B traffic = M*N*K*2/M_wave). A in LDS, double-buffered K-quarters
// (2 x 128 rows x 32 units, stride 33 -> spread banks): quarter q+1 staged
// (NT global -> regs -> ds_write) DURING quarter q's MFMAs; barrier only at
// quarter boundaries (4 total). B prefetch crosses quarter boundaries.
__global__ __launch_bounds__(1024, 4) void energy_gemm(
    const float* __restrict__ states, const short* __restrict__ WkT,
    const float* __restrict__ bk, const float* __restrict__ We,
    float* __restrict__ eraw)
{
  __shared__ short Al[2][128*33*8];    // 2 x 66 KB

  const int tid  = threadIdx.x;
  const int w    = tid >> 6;        // wave 0..15 -> col group w*64
  const int lane = tid & 63;
  const int quad = lane >> 4;       // k-unit within 32-k chunk
  const int l16  = lane & 15;
  const int m0   = blockIdx.x * 128;

  // staging: thread t owns row t>>3, units (t&7) + 8i (i=0..3) per quarter
  const int srow = tid >> 3;
  const int su0  = tid & 7;
  const float* Ag = states + (size_t)(m0 + srow)*D + su0*8;
  short* sdst = &Al[0][0];  // recomputed per quarter

  // ---- stage quarter 0 ----
#pragma unroll
  for (int i = 0; i < 4; ++i) {
    float4 x0 = ntload4(Ag + i*64);
    float4 x1 = ntload4(Ag + i*64 + 4);
    *(short8*)(&Al[0][((size_t)srow*33 + su0 + i*8)*8]) = pack8(x0, x1);
  }
  __syncthreads();

  f32x4 acc[8][4];
#pragma unroll
  for (int mi = 0; mi < 8; ++mi)
#pragma unroll
    for (int ni = 0; ni < 4; ++ni)
      acc[mi][ni] = (f32x4){0.f, 0.f, 0.f, 0.f};

  // B: fb[ni]: col = w*64 + ni*16 + l16, k-unit = kg*4 + quad
  const short* bb = WkT + ((size_t)quad*D + w*64 + l16)*8;  // + kg*32768 + ni*128

#define LOADB(kg, buf)                                                   \
  {                                                                      \
    const short* bp = bb + (size_t)(kg)*32768;                           \
    _Pragma("unroll")                                                    \
    for (int ni = 0; ni < 4; ++ni)                                       \
      buf[ni] = *(const short8*)(bp + ni*128);                           \
  }

  // A: fa[mi]: row = mi*16 + l16, unit-in-quarter = ks*4 + quad
#define LOADA(qb, ks, buf)                                               \
  {                                                                      \
    const short* ap = &Al[qb][((size_t)l16*33 + quad)*8] + (ks)*32;      \
    _Pragma("unroll")                                                    \
    for (int mi = 0; mi < 8; ++mi)                                       \
      buf[mi] = *(const short8*)(ap + mi*4224);                          \
  }

#define MFMAS(fa, fb)                                                    \
  {                                                                      \
    _Pragma("unroll")                                                    \
    for (int mi = 0; mi < 8; ++mi)                                       \
      _Pragma("unroll")                                                  \
      for (int ni = 0; ni < 4; ++ni)                                     \
        acc[mi][ni] = __builtin_amdgcn_mfma_f32_16x16x32_bf16(           \
            fa[mi], fb[ni], acc[mi][ni], 0, 0, 0);                       \
  }

  short8 fa[2][8], fb[2][4];
  LOADB(0, fb[0]);

#pragma unroll
  for (int q = 0; q < 4; ++q) {
    const int qb = q & 1, qn = qb ^ 1;

    // issue next-quarter A loads early so they complete under this
    // quarter's MFMAs (NT: bypass caches, pure stream)
    float4 sx[4][2];
    if (q < 3) {
#pragma unroll
      for (int i = 0; i < 4; ++i) {
        sx[i][0] = ntload4(Ag + (q+1)*256 + i*64);
        sx[i][1] = ntload4(Ag + (q+1)*256 + i*64 + 4);
      }
    }

    LOADA(qb, 0, fa[0]);
#pragma unroll
    for (int ks = 0; ks < 8; ++ks) {
      const int cur = ks & 1, nxt = cur ^ 1;
      if (ks < 7) {
        LOADA(qb, ks+1, fa[nxt]);
        LOADB(q*8 + ks + 1, fb[nxt]);
      } else if (q < 3) {
        LOADB(q*8 + 8, fb[nxt]);   // cross-quarter B prefetch (LDS-independent)
      }
      MFMAS(fa[cur], fb[cur]);
    }

    if (q < 3) {
#pragma unroll
      for (int i = 0; i < 4; ++i)
        *(short8*)(&Al[qn][((size_t)srow*33 + su0 + i*8)*8]) = pack8(sx[i][0], sx[i][1]);
      __syncthreads();
    }
  }

  // ---- epilogue: esum[row] += tanh(relu(c + bk[n])) * We_k[n] ----
  // acc[mi][ni][r]: row = mi*16 + quad*4 + r, col = w*64 + ni*16 + l16
  float esum[32];
#pragma unroll
  for (int qv = 0; qv < 32; ++qv) esum[qv] = 0.f;
#pragma unroll
  for (int ni = 0; ni < 4; ++ni) {
    const int n = w*64 + ni*16 + l16;
    const float bkv = bk[n];
    const float wev = We[D + n];
#pragma unroll
    for (int mi = 0; mi < 8; ++mi)
#pragma unroll
      for (int r = 0; r < 4; ++r) {
        float x = acc[mi][ni][r] + bkv;
        x = fmaxf(x, 0.f);
        float ex = __expf(2.f * x);
        float th = 1.f - 2.f/(ex + 1.f);
        esum[mi*4 + r] += th * wev;
      }
  }
#pragma unroll
  for (int dd = 1; dd < 16; dd <<= 1)
#pragma unroll
    for (int qv = 0; qv < 32; ++qv)
      esum[qv] += __shfl_xor(esum[qv], dd, 64);

  __syncthreads();                    // all waves done with Al
  float* red = (float*)&Al[0][0];     // [128 rows][16 waves]
  if (l16 == 0) {
#pragma unroll
    for (int mi = 0; mi < 8; ++mi)
#pragma unroll
      for (int r = 0; r < 4; ++r)
        red[(mi*16 + quad*4 + r)*16 + w] = esum[mi*4 + r];
  }
  __syncthreads();
  if (tid < 128) {
    float s = 0.f;
#pragma unroll
    for (int wi = 0; wi < 16; ++wi) s += red[tid*16 + wi];
    eraw[m0 + tid] = s;
  }
#undef LOADB
#undef LOADA
#undef MFMAS
}

// ---------------- Kernel 3: row softmax eraw -> wts (d_out) ----------------
__global__ __launch_bounds__(256) void softmax_rows(
    const float* __restrict__ eraw, float* __restrict__ wts) {
  const int b = blockIdx.x, t = threadIdx.x;
  __shared__ float red[256];
  float v[8];
  float m = -1e30f;
#pragma unroll
  for (int j = 0; j < 8; ++j) {
    v[j] = eraw[(size_t)b*SLEN + j*256 + t];
    m = fmaxf(m, v[j]);
  }
  red[t] = m; __syncthreads();
  for (int s = 128; s > 0; s >>= 1) {
    if (t < s) red[t] = fmaxf(red[t], red[t+s]);
    __syncthreads();
  }
  m = red[0];
  __syncthreads();
  float sum = 0.f;
#pragma unroll
  for (int j = 0; j < 8; ++j) { v[j] = __expf(v[j] - m); sum += v[j]; }
  red[t] = sum; __syncthreads();
  for (int s = 128; s > 0; s >>= 1) {
    if (t < s) red[t] += red[t+s];
    __syncthreads();
  }
  const float inv = 1.f / red[0];
#pragma unroll
  for (int j = 0; j < 8; ++j)
    wts[(size_t)b*SLEN + j*256 + t] = v[j] * inv;
}

// ---------------- Kernel 4: attn partials, 1024 blocks (BW-saturating) ------
// part[(b*64+sc)*1024 + d] = sum_{32 s in chunk} w[b,s]*states[b,s,d]
__global__ __launch_bounds__(256) void attn_partial(
    const float* __restrict__ states, const float* __restrict__ wts,
    float* __restrict__ part)
{
  const int sc = blockIdx.x;   // 0..63 (32 s each)
  const int b  = blockIdx.y;   // 0..15
  const int t  = threadIdx.x;
  __shared__ float wsh[32];
  if (t < 32) wsh[t] = wts[(size_t)b*SLEN + sc*32 + t];
  __syncthreads();
  const float* sp = states + ((size_t)b*SLEN + sc*32)*D + t*4;
  float ax = 0.f, ay = 0.f, az = 0.f, aw = 0.f;
#pragma unroll
  for (int s = 0; s < 32; ++s) {
    float4 x = *(const float4*)(sp + (size_t)s*D);
    const float wv = wsh[s];
    ax = fmaf(wv, x.x, ax);
    ay = fmaf(wv, x.y, ay);
    az = fmaf(wv, x.z, az);
    aw = fmaf(wv, x.w, aw);
  }
  float4 o; o.x = ax; o.y = ay; o.z = az; o.w = aw;
  *(float4*)(part + ((size_t)(b*64 + sc))*D + t*4) = o;
}

// ---------------- Kernel 5: reduce 64 partials per batch ----------------
__global__ __launch_bounds__(256) void attn_final(
    const float* __restrict__ part, float* __restrict__ attn)
{
  const int b = blockIdx.x, t = threadIdx.x;
  float4 s = {0.f, 0.f, 0.f, 0.f};
#pragma unroll
  for (int sc = 0; sc < 64; ++sc) {
    float4 v = *(const float4*)(part + ((size_t)(b*64 + sc))*D + t*4);
    s.x += v.x; s.y += v.y; s.z += v.z; s.w += v.w;
  }
  *(float4*)(attn + (size_t)b*D + t*4) = s;
}

extern "C" void kernel_launch(void* const* d_in, const int* in_sizes, int n_in,
                              void* d_out, int out_size, void* d_ws, size_t ws_size,
                              hipStream_t stream) {
  // inputs: 0=query 1=states 2=Wq 3=bq 4=Wk 5=bk 6=We 7=be
  // q-path terms are constant per softmax row -> cancel; dead code.
  const float* states = (const float*)d_in[1];
  const float* Wk     = (const float*)d_in[4];
  const float* bk     = (const float*)d_in[5];
  const float* We     = (const float*)d_in[6];
  float* out = (float*)d_out;            // [0:32768) attn_weights, [32768:49152) attn

  short* WkT  = (short*)d_ws;                                         // 2 MB
  float* eraw = (float*)((char*)d_ws + (size_t)D*D*sizeof(short));    // 128 KB
  float* part = (float*)((char*)d_ws + (size_t)D*D*sizeof(short)
                                     + (size_t)MROWS*sizeof(float));  // 4 MB

  (void)in_sizes; (void)n_in; (void)out_size; (void)ws_size;

  wk_prep<<<128, 256, 0, stream>>>(Wk, WkT);
  energy_gemm<<<MROWS/128, 1024, 0, stream>>>(states, WkT, bk, We, eraw);
  softmax_rows<<<BS, 256, 0, stream>>>(eraw, out);
  attn_partial<<<dim3(64, BS), 256, 0, stream>>>(states, out, part);
  attn_final<<<BS, 256, 0, stream>>>(part, out + MROWS);
}

// Round 8
// 311.866 us; speedup vs baseline: 2.7303x; 2.7303x over previous
//
#include <hip/hip_runtime.h>
#include <hip/hip_bf16.h>

#define D 1024
#define SLEN 2048
#define BS 16
#define MROWS (BS*SLEN)   // 32768

typedef __attribute__((ext_vector_type(8))) short short8;
typedef __attribute__((ext_vector_type(4))) float f32x4;

__device__ __forceinline__ short f2bf(float f) {
  __hip_bfloat16 h = __float2bfloat16(f);
  return __builtin_bit_cast(short, h);
}

__device__ __forceinline__ short8 pack8(const float4& a, const float4& b) {
  short8 p;
  p[0]=f2bf(a.x); p[1]=f2bf(a.y); p[2]=f2bf(a.z); p[3]=f2bf(a.w);
  p[4]=f2bf(b.x); p[5]=f2bf(b.y); p[6]=f2bf(b.z); p[7]=f2bf(b.w);
  return p;
}

// ---------------- Kernel 1: Wk (k,n) fp32 -> blocked bf16 WkT ----------------
// WkT[(u*1024 + n)*8 + j] = bf16(Wk[(u*8+j)*1024 + n]), u=0..127.
// 16B slot (u,n) = B[n][k=u*8..u*8+7] = one MFMA B k-unit.
__global__ __launch_bounds__(256) void wk_prep(const float* __restrict__ Wk,
                                               short* __restrict__ WkT) {
  const int g = blockIdx.x;        // 0..127
  const int t = threadIdx.x;
#pragma unroll
  for (int it = 0; it < 4; ++it) {
    const int n = it*256 + t;
    short8 p;
#pragma unroll
    for (int j = 0; j < 8; ++j)
      p[j] = f2bf(Wk[(size_t)(g*8 + j)*D + n]);
    *(short8*)(WkT + ((size_t)g*D + n)*8) = p;
  }
}

// ---------------- Kernel 2: energy GEMM v4 ----------------
// 512 blocks x 512 thr (8 waves = 2/SIMD, 256 regs/wave). Block = 128 rows x
// 512 cols (N split 2 -> eraw atomicAdd). Wave tile 128x64 (8x4 MFMA
// 16x16x32, acc=128): B L1 traffic = 26 B/cyc/CU (vs 64 ceiling; the 64-row
// tile was at ~100% -> that was the round-5 wall). A in LDS as K-eighths
// (2 x 128 rows x 16 units, stride 17 -> conflict-free), double-buffered:
// eighth e+1's global loads issue at top of eighth e's compute, ds_write at
// its end; barrier every 4 k-steps (~5k cyc apart). fb depth-1 ring (budget
// ~1241 cyc >> L2/L3 latency). NO launch-bounds over-subscription (r7 lesson:
// 1024-thr blocks cap regs at 128/wave -> total spill).
__global__ __launch_bounds__(512, 2) void energy_gemm(
    const float* __restrict__ states, const short* __restrict__ WkT,
    const float* __restrict__ bk, const float* __restrict__ We,
    float* __restrict__ eraw)
{
  __shared__ short Al[2][128*17*8];    // 2 x 34 KB

  const int tid  = threadIdx.x;
  const int w    = tid >> 6;        // wave 0..7 -> col group w*64
  const int lane = tid & 63;
  const int quad = lane >> 4;       // k-unit within 32-k chunk
  const int l16  = lane & 15;
  const int m0   = (blockIdx.x >> 1) * 128;
  const int n0   = (blockIdx.x & 1) * 512;

  // staging map: thread t -> row t>>2, units (t&3)*4 .. +3 of the eighth
  const int srow = tid >> 2;
  const int su   = (tid & 3) * 4;
  const float* Ag = states + (size_t)(m0 + srow)*D + su*8;

  // ---- stage eighth 0 ----
  {
#pragma unroll
    for (int j = 0; j < 4; ++j) {
      float4 x0 = *(const float4*)(Ag + j*8);
      float4 x1 = *(const float4*)(Ag + j*8 + 4);
      *(short8*)(&Al[0][((size_t)srow*17 + su + j)*8]) = pack8(x0, x1);
    }
  }
  __syncthreads();

  f32x4 acc[8][4];
#pragma unroll
  for (int mi = 0; mi < 8; ++mi)
#pragma unroll
    for (int ni = 0; ni < 4; ++ni)
      acc[mi][ni] = (f32x4){0.f, 0.f, 0.f, 0.f};

  // B frag: col = n0 + w*64 + ni*16 + l16, global k-unit = kg*4 + quad
  const short* bb = WkT + ((size_t)quad*D + n0 + w*64 + l16)*8;

#define LOADB(kg, buf)                                                   \
  {                                                                      \
    const short* bp = bb + (size_t)(kg)*32768;                           \
    _Pragma("unroll")                                                    \
    for (int ni = 0; ni < 4; ++ni)                                       \
      buf[ni] = *(const short8*)(bp + ni*128);                           \
  }

  // A frag: row = mi*16 + l16, unit-in-eighth = ks*4 + quad
#define LOADA(qb, ks, buf)                                               \
  {                                                                      \
    const short* ap = &Al[qb][((size_t)l16*17 + (ks)*4 + quad)*8];       \
    _Pragma("unroll")                                                    \
    for (int mi = 0; mi < 8; ++mi)                                       \
      buf[mi] = *(const short8*)(ap + mi*2176);                          \
  }

#define MFMAS(fa, fb)                                                    \
  {                                                                      \
    _Pragma("unroll")                                                    \
    for (int mi = 0; mi < 8; ++mi)                                       \
      _Pragma("unroll")                                                  \
      for (int ni = 0; ni < 4; ++ni)                                     \
        acc[mi][ni] = __builtin_amdgcn_mfma_f32_16x16x32_bf16(           \
            fa[mi], fb[ni], acc[mi][ni], 0, 0, 0);                       \
  }

  short8 fa[8], fb[2][4];
  LOADB(0, fb[0]);

  for (int e = 0; e < 8; ++e) {
    const int buf = e & 1;

    // issue next-eighth A loads early; consumed (pack+ds_write) at eighth end
    float4 sx[4][2];
    if (e < 7) {
#pragma unroll
      for (int j = 0; j < 4; ++j) {
        sx[j][0] = *(const float4*)(Ag + (e+1)*128 + j*8);
        sx[j][1] = *(const float4*)(Ag + (e+1)*128 + j*8 + 4);
      }
    }

#pragma unroll
    for (int ks = 0; ks < 4; ++ks) {
      const int kg = e*4 + ks;
      if (kg < 31) LOADB(kg + 1, fb[(kg + 1) & 1]);
      LOADA(buf, ks, fa);
      MFMAS(fa, fb[kg & 1]);
    }

    if (e < 7) {
#pragma unroll
      for (int j = 0; j < 4; ++j)
        *(short8*)(&Al[buf ^ 1][((size_t)srow*17 + su + j)*8]) = pack8(sx[j][0], sx[j][1]);
      __syncthreads();
    }
  }

  // ---- epilogue: esum[row] += tanh(relu(c + bk[n])) * We_k[n] ----
  // acc[mi][ni][r]: row = mi*16 + quad*4 + r, col = n0 + w*64 + ni*16 + l16
  float esum[32];
#pragma unroll
  for (int qv = 0; qv < 32; ++qv) esum[qv] = 0.f;
#pragma unroll
  for (int ni = 0; ni < 4; ++ni) {
    const int n = n0 + w*64 + ni*16 + l16;
    const float bkv = bk[n];
    const float wev = We[D + n];
#pragma unroll
    for (int mi = 0; mi < 8; ++mi)
#pragma unroll
      for (int r = 0; r < 4; ++r) {
        float x = acc[mi][ni][r] + bkv;
        x = fmaxf(x, 0.f);
        float ex = __expf(2.f * x);
        float th = 1.f - 2.f/(ex + 1.f);
        esum[mi*4 + r] += th * wev;
      }
  }
#pragma unroll
  for (int dd = 1; dd < 16; dd <<= 1)
#pragma unroll
    for (int qv = 0; qv < 32; ++qv)
      esum[qv] += __shfl_xor(esum[qv], dd, 64);

  __syncthreads();                    // all waves done with Al
  float* red = (float*)&Al[0][0];     // [128 rows][8 waves]
  if (l16 == 0) {
#pragma unroll
    for (int mi = 0; mi < 8; ++mi)
#pragma unroll
      for (int r = 0; r < 4; ++r)
        red[(mi*16 + quad*4 + r)*8 + w] = esum[mi*4 + r];
  }
  __syncthreads();
  if (tid < 128) {
    float s = 0.f;
#pragma unroll
    for (int wi = 0; wi < 8; ++wi) s += red[tid*8 + wi];
    atomicAdd(eraw + m0 + tid, s);
  }
#undef LOADB
#undef LOADA
#undef MFMAS
}

// ---------------- Kernel 3: row softmax eraw -> wts (d_out) ----------------
__global__ __launch_bounds__(256) void softmax_rows(
    const float* __restrict__ eraw, float* __restrict__ wts) {
  const int b = blockIdx.x, t = threadIdx.x;
  __shared__ float red[256];
  float v[8];
  float m = -1e30f;
#pragma unroll
  for (int j = 0; j < 8; ++j) {
    v[j] = eraw[(size_t)b*SLEN + j*256 + t];
    m = fmaxf(m, v[j]);
  }
  red[t] = m; __syncthreads();
  for (int s = 128; s > 0; s >>= 1) {
    if (t < s) red[t] = fmaxf(red[t], red[t+s]);
    __syncthreads();
  }
  m = red[0];
  __syncthreads();
  float sum = 0.f;
#pragma unroll
  for (int j = 0; j < 8; ++j) { v[j] = __expf(v[j] - m); sum += v[j]; }
  red[t] = sum; __syncthreads();
  for (int s = 128; s > 0; s >>= 1) {
    if (t < s) red[t] += red[t+s];
    __syncthreads();
  }
  const float inv = 1.f / red[0];
#pragma unroll
  for (int j = 0; j < 8; ++j)
    wts[(size_t)b*SLEN + j*256 + t] = v[j] * inv;
}

// ---------------- Kernel 4: attn partials, 1024 blocks (BW-saturating) ------
// part[(b*64+sc)*1024 + d] = sum_{32 s in chunk} w[b,s]*states[b,s,d]
__global__ __launch_bounds__(256) void attn_partial(
    const float* __restrict__ states, const float* __restrict__ wts,
    float* __restrict__ part)
{
  const int sc = blockIdx.x;   // 0..63 (32 s each)
  const int b  = blockIdx.y;   // 0..15
  const int t  = threadIdx.x;
  __shared__ float wsh[32];
  if (t < 32) wsh[t] = wts[(size_t)b*SLEN + sc*32 + t];
  __syncthreads();
  const float* sp = states + ((size_t)b*SLEN + sc*32)*D + t*4;
  float ax = 0.f, ay = 0.f, az = 0.f, aw = 0.f;
#pragma unroll
  for (int s = 0; s < 32; ++s) {
    float4 x = *(const float4*)(sp + (size_t)s*D);
    const float wv = wsh[s];
    ax = fmaf(wv, x.x, ax);
    ay = fmaf(wv, x.y, ay);
    az = fmaf(wv, x.z, az);
    aw = fmaf(wv, x.w, aw);
  }
  float4 o; o.x = ax; o.y = ay; o.z = az; o.w = aw;
  *(float4*)(part + ((size_t)(b*64 + sc))*D + t*4) = o;
}

// ---------------- Kernel 5: reduce 64 partials per batch ----------------
__global__ __launch_bounds__(256) void attn_final(
    const float* __restrict__ part, float* __restrict__ attn)
{
  const int b = blockIdx.x, t = threadIdx.x;
  float4 s = {0.f, 0.f, 0.f, 0.f};
#pragma unroll
  for (int sc = 0; sc < 64; ++sc) {
    float4 v = *(const float4*)(part + ((size_t)(b*64 + sc))*D + t*4);
    s.x += v.x; s.y += v.y; s.z += v.z; s.w += v.w;
  }
  *(float4*)(attn + (size_t)b*D + t*4) = s;
}

extern "C" void kernel_launch(void* const* d_in, const int* in_sizes, int n_in,
                              void* d_out, int out_size, void* d_ws, size_t ws_size,
                              hipStream_t stream) {
  // inputs: 0=query 1=states 2=Wq 3=bq 4=Wk 5=bk 6=We 7=be
  // q-path terms are constant per softmax row -> cancel; dead code.
  const float* states = (const float*)d_in[1];
  const float* Wk     = (const float*)d_in[4];
  const float* bk     = (const float*)d_in[5];
  const float* We     = (const float*)d_in[6];
  float* out = (float*)d_out;            // [0:32768) attn_weights, [32768:49152) attn

  short* WkT  = (short*)d_ws;                                         // 2 MB
  float* eraw = (float*)((char*)d_ws + (size_t)D*D*sizeof(short));    // 128 KB
  float* part = (float*)((char*)d_ws + (size_t)D*D*sizeof(short)
                                     + (size_t)MROWS*sizeof(float));  // 4 MB

  (void)in_sizes; (void)n_in; (void)out_size; (void)ws_size;

  hipMemsetAsync(eraw, 0, (size_t)MROWS*sizeof(float), stream);
  wk_prep<<<128, 256, 0, stream>>>(Wk, WkT);
  energy_gemm<<<512, 512, 0, stream>>>(states, WkT, bk, We, eraw);
  softmax_rows<<<BS, 256, 0, stream>>>(eraw, out);
  attn_partial<<<dim3(64, BS), 256, 0, stream>>>(states, out, part);
  attn_final<<<BS, 256, 0, stream>>>(part, out + MROWS);
}